// Round 6
// baseline (144.362 us; speedup 1.0000x reference)
//
#include <hip/hip_runtime.h>
#include <hip/hip_bf16.h>

#define N_NODES 100000
#define N_EDGES 1600000
#define K_DIM 128
#define N_DIM 128
#define BM_WORDS 3125        // ceil(100000/32); 3125*32 = 100000 exactly
#define PART_STRIDE 3136     // per-block partial-mask stride (64B multiple)
#define FLAG_BLOCKS 64       // 25000 edges per block

typedef __attribute__((ext_vector_type(8))) short bf16x8;   // 8 bf16 = 4 VGPRs
typedef __attribute__((ext_vector_type(4))) float f32x4;    // MFMA accumulator

__device__ inline unsigned short f2bf(float f) {
    __hip_bfloat16 b = __float2bfloat16(f);
    return __builtin_bit_cast(unsigned short, b);
}

// Phase A: per-block private "has incoming edge" bitmask in LDS (LDS atomics
// only -> no LLC hot-line serialization), stored to a disjoint partial region
// with plain coalesced stores.
__global__ __launch_bounds__(256)
void flag_partial(const int* __restrict__ ei, unsigned int* __restrict__ parts) {
    __shared__ unsigned int lbm[BM_WORDS];
    for (int i = threadIdx.x; i < BM_WORDS; i += 256) lbm[i] = 0;
    __syncthreads();

    // int64-as-int32-pairs vs int32 sniff (high words of non-neg int64 are 0)
    bool is64 = ((ei[1] | ei[3] | ei[5] | ei[7]) == 0);
    const int base = blockIdx.x * (N_EDGES / FLAG_BLOCKS);   // 25000/block
    if (is64) {
        // col values at words [2E,4E), stride 2; uint4 = 2 edges, 16B-aligned
        const uint4* p = (const uint4*)(ei + 2 * N_EDGES + 2 * base);
        for (int t = threadIdx.x; t < 12500; t += 256) {
            uint4 v = p[t];
            atomicOr(&lbm[v.x >> 5], 1u << (v.x & 31));
            atomicOr(&lbm[v.z >> 5], 1u << (v.z & 31));
        }
    } else {
        const uint2* p = (const uint2*)(ei + N_EDGES + base);
        for (int t = threadIdx.x; t < 12500; t += 256) {
            uint2 v = p[t];
            atomicOr(&lbm[v.x >> 5], 1u << (v.x & 31));
            atomicOr(&lbm[v.y >> 5], 1u << (v.y & 31));
        }
    }
    __syncthreads();

    unsigned int* dst = parts + (size_t)blockIdx.x * PART_STRIDE;
    for (int i = threadIdx.x; i < BM_WORDS; i += 256) dst[i] = lbm[i];
}

// Phase B: OR the 64 partials per word; for the (expected ~0: e^-16 per node)
// nodes with NO incoming edge, zero their output row.  Coalesced loads (lanes
// sweep word index), rare divergent fixup path.
__global__ __launch_bounds__(256)
void reduce_fixup(const unsigned int* __restrict__ parts,
                  float* __restrict__ out) {
    int i = blockIdx.x * 256 + threadIdx.x;
    if (i >= BM_WORDS) return;
    unsigned int v = 0;
#pragma unroll 8
    for (int b = 0; b < FLAG_BLOCKS; ++b)
        v |= parts[(size_t)b * PART_STRIDE + i];
    if (v != 0xFFFFFFFFu) {
        unsigned int z = ~v;
        while (z) {
            int bit = __ffs(z) - 1;
            z &= z - 1;
            long n = (long)i * 32 + bit;         // always < 100000 (exact fit)
            f32x4* row = (f32x4*)(out + n * N_DIM);
#pragma unroll
            for (int j = 0; j < N_DIM / 4; ++j) row[j] = (f32x4){0.f, 0.f, 0.f, 0.f};
        }
    }
}

// out[n,:] = (x @ W)[n,:], unmasked (mask fixup handled by reduce_fixup).
// fp32 in, bf16 MFMA, fp32 accumulate/store.  256 rows/block, 4 m-tiles/wave,
// W staged to LDS once per block, conflict-free (ds_write_b128, word stride 68).
__global__ __launch_bounds__(256, 2)
void gemm_kernel(const float* __restrict__ xf,
                 const float* __restrict__ wf,
                 float* __restrict__ out) {
    // Column-major bf16 W: ldsW[n*136 + k]. 272 B stride: 16B-aligned for
    // b128; word stride 68 -> lane bank starts 0,4,...,28 -> conflict-free.
    __shared__ __attribute__((aligned(16))) unsigned short ldsW[N_DIM * 136];

    const int tid = threadIdx.x;

    // Transpose-read staging: coalesced global reads along n (W is 64 KB,
    // L2-resident across 391 blocks).
#pragma unroll
    for (int i = 0; i < 8; ++i) {
        int c = i * 256 + tid;            // 0..2047
        int n = c & 127;
        int k0 = (c >> 7) << 3;           // 0,8,...,120
        unsigned short tmp[8];
#pragma unroll
        for (int j = 0; j < 8; ++j) tmp[j] = f2bf(wf[(k0 + j) * N_DIM + n]);
        *(uint4*)(ldsW + n * 136 + k0) = *(const uint4*)tmp;
    }
    __syncthreads();

    const int lane = tid & 63;
    const int wave = tid >> 6;
    const int m    = lane & 15;   // A row / B col / C col
    const int quad = lane >> 4;   // 0..3

    const int rb = blockIdx.x * 256 + wave * 64;   // wave's first row

    int rowc[4];
#pragma unroll
    for (int mt = 0; mt < 4; ++mt) {
        int r = rb + mt * 16 + m;
        rowc[mt] = r < N_NODES ? r : (N_NODES - 1);   // clamp: loads stay safe
    }

    f32x4 acc[4][8];
#pragma unroll
    for (int mt = 0; mt < 4; ++mt)
#pragma unroll
        for (int t = 0; t < 8; ++t) acc[mt][t] = (f32x4){0.f, 0.f, 0.f, 0.f};

#pragma unroll
    for (int kk = 0; kk < 4; ++kk) {
        const int kbase = kk * 32 + quad * 8;
        bf16x8 af[4];
#pragma unroll
        for (int mt = 0; mt < 4; ++mt) {
            f32x4 a0 = *(const f32x4*)(xf + rowc[mt] * K_DIM + kbase);
            f32x4 a1 = *(const f32x4*)(xf + rowc[mt] * K_DIM + kbase + 4);
            unsigned short t8[8];
#pragma unroll
            for (int j = 0; j < 4; ++j) {
                t8[j]     = f2bf(a0[j]);
                t8[4 + j] = f2bf(a1[j]);
            }
            af[mt] = *(const bf16x8*)t8;
        }
#pragma unroll
        for (int t = 0; t < 8; ++t) {
            bf16x8 bfrag = *(const bf16x8*)(ldsW + (t * 16 + m) * 136 + kbase);
#pragma unroll
            for (int mt = 0; mt < 4; ++mt)
                acc[mt][t] = __builtin_amdgcn_mfma_f32_16x16x32_bf16(
                    af[mt], bfrag, acc[mt][t], 0, 0, 0);
        }
    }

    // C/D layout: col = lane&15, row = quad*4 + reg
#pragma unroll
    for (int mt = 0; mt < 4; ++mt) {
#pragma unroll
        for (int r = 0; r < 4; ++r) {
            int orow = rb + mt * 16 + quad * 4 + r;
            if (orow < N_NODES) {
#pragma unroll
                for (int t = 0; t < 8; ++t)
                    out[orow * N_DIM + t * 16 + m] = acc[mt][t][r];
            }
        }
    }
}

extern "C" void kernel_launch(void* const* d_in, const int* in_sizes, int n_in,
                              void* d_out, int out_size, void* d_ws, size_t ws_size,
                              hipStream_t stream) {
    const float* x = (const float*)d_in[0];
    const float* w = (const float*)d_in[1];
    // d_in[2] (att) is mathematically irrelevant: normalized attention weights
    // sum to s/(s+1e-16) == 1 per segment in fp32, and the reference
    // aggregates h[col]*alpha into col, so out[n] = h[n] (or 0 if no in-edge).
    const int* ei = (const int*)d_in[3];
    float* out = (float*)d_out;

    unsigned int* parts = (unsigned int*)d_ws;   // 64 partial bitmasks

    gemm_kernel<<<(N_NODES + 255) / 256, 256, 0, stream>>>(x, w, out);
    flag_partial<<<FLAG_BLOCKS, 256, 0, stream>>>(ei, parts);
    reduce_fixup<<<(BM_WORDS + 255) / 256, 256, 0, stream>>>(parts, out);
}